// Round 15
// baseline (99.618 us; speedup 1.0000x reference)
//
#include <hip/hip_runtime.h>
#include <hip/hip_bf16.h>
#include <math.h>

typedef __attribute__((ext_vector_type(8))) short bf16x8;
typedef __attribute__((ext_vector_type(4))) float f32x4;
typedef __attribute__((ext_vector_type(2))) float f32x2;

constexpr int B_ = 4096;
constexpr int N_ = 8192;   // 2B rows
constexpr int D_ = 128;
constexpr float INV_T = 2.0f;              // 1/temperature
constexpr float EXP2C = 2.0f * 1.4426950408889634f;  // (1/T)*log2(e) for exp2
constexpr float E2C = 7.38905609893065f;   // exp(2) — diagonal self-sim term

constexpr int TILE = 128;                  // symmetric tile edge
constexpr int NTI  = N_ / TILE;            // 64 tiles per dim
constexpr int NBLK = NTI * (NTI + 1) / 2;  // 2080 upper-tri blocks
constexpr int NPAN = TILE / 16;            // 8 column panels per wave

// ZF fragment-major layout: row j, element e  ->  short index
//   (j>>4)*2048 + (e>>3)*128 + (j&15)*8 + (e&7)
// wave fragment load (16-row panel p, k-slice s): contiguous 1KB at
//   p*2048 + s*512 + lane*8   (lane i exactly at byte i*16).

// ------- Kernel A: normalize pair -> ZF rows p & p+B, pos[p] -----------------
__global__ __launch_bounds__(256) void nrm_kernel(const float* __restrict__ ei,
                                                  const float* __restrict__ ej,
                                                  short* __restrict__ zf,
                                                  float* __restrict__ pos,
                                                  float* __restrict__ out) {
    int p    = (blockIdx.x * blockDim.x + threadIdx.x) >> 6;  // pair id
    int lane = threadIdx.x & 63;
    if (p >= B_) return;
    f32x2 a = *(const f32x2*)(ei + (size_t)p * D_ + lane * 2);
    f32x2 b = *(const f32x2*)(ej + (size_t)p * D_ + lane * 2);
    float na = a.x * a.x + a.y * a.y;
    float nb = b.x * b.x + b.y * b.y;
    float dt = a.x * b.x + a.y * b.y;
    #pragma unroll
    for (int m = 1; m < 64; m <<= 1) {
        na += __shfl_xor(na, m);
        nb += __shfl_xor(nb, m);
        dt += __shfl_xor(dt, m);
    }
    float ra = rsqrtf(na), rb = rsqrtf(nb);
    __hip_bfloat162 oa, ob;
    oa.x = __float2bfloat16(a.x * ra); oa.y = __float2bfloat16(a.y * ra);
    ob.x = __float2bfloat16(b.x * rb); ob.y = __float2bfloat16(b.y * rb);
    size_t fi = (size_t)(lane >> 2) * 128 + (p & 15) * 8 + (lane & 3) * 2;
    *(__hip_bfloat162*)(zf + (size_t)(p >> 4) * 2048 + fi)        = oa;
    *(__hip_bfloat162*)(zf + (size_t)((p + B_) >> 4) * 2048 + fi) = ob;
    if (lane == 0) {
        pos[p] = dt * ra * rb;
        if (p == 0) out[0] = 0.0f;
    }
}

// ------- Kernel B: symmetric fused sim/exp/row+col partial sums --------------
// Upper-triangle 128x128 tiles: block (bi,bj), bj>=bi; 2 waves x 64 rows.
// Each exp(2*sim[i][j]) feeds row i's partial AND (via symmetry) row j's
// partial (as a column sum). part[c][k] slots are written by exactly one
// block: c>blk(k) row-type by block (blk(k),c); c<blk(k) col-type by block
// (c,blk(k)); c==blk(k) diagonal row-type. No atomics.
__global__ __launch_bounds__(128) void simsum_kernel(const short* __restrict__ zf,
                                                     float* __restrict__ part) {
    int lane = threadIdx.x & 63;
    int wave = threadIdx.x >> 6;                        // 0..1
    // decode upper-tri tile (scalar, uniform)
    int bi = 0, rem = blockIdx.x;
    while (rem >= NTI - bi) { rem -= NTI - bi; ++bi; }
    int bj = bi + rem;

    int g  = lane >> 4;
    int lm = lane & 15;

    const short* ZA = zf + (size_t)(bi * 8 + wave * 4) * 2048 + lane * 8;
    const short* ZB = zf + (size_t)(bj * 8) * 2048 + lane * 8;

    // A fragments: 4 row-panels (64 rows) x 4 k-slices, contiguous 1KB loads
    bf16x8 a[4][4];
    #pragma unroll
    for (int t = 0; t < 4; ++t)
        #pragma unroll
        for (int s = 0; s < 4; ++s)
            a[t][s] = *(const bf16x8*)(ZA + t * 2048 + s * 512);

    f32x4 rs[4];
    #pragma unroll
    for (int t = 0; t < 4; ++t) rs[t] = f32x4{0.f, 0.f, 0.f, 0.f};
    float cs[NPAN];

    // depth-2 rotating register prefetch over the 8 column panels
    bf16x8 b[3][4];
    #pragma unroll
    for (int s = 0; s < 4; ++s) b[0][s] = *(const bf16x8*)(ZB + 0 * 2048 + s * 512);
    #pragma unroll
    for (int s = 0; s < 4; ++s) b[1][s] = *(const bf16x8*)(ZB + 1 * 2048 + s * 512);

    #pragma unroll
    for (int jt = 0; jt < NPAN; ++jt) {
        if (jt + 2 < NPAN) {
            #pragma unroll
            for (int s = 0; s < 4; ++s)
                b[(jt + 2) % 3][s] = *(const bf16x8*)(ZB + (size_t)(jt + 2) * 2048 + s * 512);
        }
        f32x4 acc[4];
        #pragma unroll
        for (int t = 0; t < 4; ++t) acc[t] = f32x4{0.f, 0.f, 0.f, 0.f};
        #pragma unroll
        for (int s = 0; s < 4; ++s)
            #pragma unroll
            for (int t = 0; t < 4; ++t)
                acc[t] = __builtin_amdgcn_mfma_f32_16x16x32_bf16(a[t][s], b[jt % 3][s], acc[t], 0, 0, 0);
        float ca = 0.f;
        #pragma unroll
        for (int t = 0; t < 4; ++t)
            #pragma unroll
            for (int r = 0; r < 4; ++r) {
                float e = exp2f(EXP2C * acc[t][r]);
                rs[t][r] += e;
                ca += e;
            }
        // column sum over this wave's 64 rows: reduce across g-groups
        ca += __shfl_xor(ca, 16);
        ca += __shfl_xor(ca, 32);
        cs[jt] = ca;          // col = jt*16 + lm (valid in all lanes)
    }

    // row sums: reduce across the 16 column-lanes (low 4 lane bits)
    #pragma unroll
    for (int m = 1; m < 16; m <<= 1)
        #pragma unroll
        for (int t = 0; t < 4; ++t)
            #pragma unroll
            for (int r = 0; r < 4; ++r)
                rs[t][r] += __shfl_xor(rs[t][r], m);

    if (lm == 0) {
        float* pr = part + (size_t)bj * N_ + bi * TILE + wave * 64;
        #pragma unroll
        for (int t = 0; t < 4; ++t)
            #pragma unroll
            for (int r = 0; r < 4; ++r)
                pr[t * 16 + g * 4 + r] = rs[t][r];
    }

    // column partials: combine the 2 waves via LDS, single write per block
    __shared__ float lds[2 * TILE];
    if (lane < 16) {
        #pragma unroll
        for (int jt = 0; jt < NPAN; ++jt)
            lds[wave * TILE + jt * 16 + lane] = cs[jt];
    }
    __syncthreads();
    if (bi != bj) {
        int tid = threadIdx.x;   // 0..127
        float v = lds[tid] + lds[TILE + tid];
        part[(size_t)bi * N_ + bj * TILE + tid] = v;
    }
}

// ------- Kernel C: loss = mean(log(sum_c part[c][k] - e^2) - 2*pos) ----------
__global__ __launch_bounds__(256) void loss_kernel(const float* __restrict__ part,
                                                   const float* __restrict__ pos,
                                                   float* __restrict__ out) {
    int tid = threadIdx.x;
    int k   = blockIdx.x * 256 + tid;
    float d = 0.0f;
    #pragma unroll
    for (int c = 0; c < NTI; ++c) d += part[(size_t)c * N_ + k];
    d -= E2C;
    float v = __logf(d) - pos[k & (B_ - 1)] * INV_T;
    #pragma unroll
    for (int m = 1; m < 64; m <<= 1) v += __shfl_xor(v, m);
    __shared__ float ps[4];
    if ((tid & 63) == 0) ps[tid >> 6] = v;
    __syncthreads();
    if (tid == 0)
        atomicAdd(out, (ps[0] + ps[1] + ps[2] + ps[3]) * (1.0f / N_));
}

// ------- launch --------------------------------------------------------------
extern "C" void kernel_launch(void* const* d_in, const int* in_sizes, int n_in,
                              void* d_out, int out_size, void* d_ws, size_t ws_size,
                              hipStream_t stream) {
    const float* ei = (const float*)d_in[0];
    const float* ej = (const float*)d_in[1];
    float* out = (float*)d_out;

    short* zf   = (short*)d_ws;                                       // 2 MB
    float* pos  = (float*)((char*)d_ws + (size_t)N_ * D_ * 2);        // 16 KB
    float* part = pos + B_;                                           // NTI*N_*4 = 2 MB

    nrm_kernel<<<dim3(B_ / 4), dim3(256), 0, stream>>>(ei, ej, zf, pos, out);
    simsum_kernel<<<dim3(NBLK), dim3(128), 0, stream>>>(zf, part);
    loss_kernel<<<dim3(N_ / 256), dim3(256), 0, stream>>>(part, pos, out);
}

// Round 16
// 96.611 us; speedup vs baseline: 1.0311x; 1.0311x over previous
//
#include <hip/hip_runtime.h>
#include <hip/hip_bf16.h>
#include <math.h>

typedef __attribute__((ext_vector_type(8))) short bf16x8;
typedef __attribute__((ext_vector_type(4))) float f32x4;
typedef __attribute__((ext_vector_type(2))) float f32x2;

constexpr int B_ = 4096;
constexpr int N_ = 8192;   // 2B rows
constexpr int D_ = 128;
constexpr float INV_T = 2.0f;              // 1/temperature
constexpr float EXP2C = 2.0f * 1.4426950408889634f;  // (1/T)*log2(e) for exp2
constexpr float E2C = 7.38905609893065f;   // exp(2) — diagonal self-sim term

constexpr int NJ = 32;
constexpr int BLK_ROWS = 128;              // 4 waves x 32 rows
constexpr int JCHUNK = N_ / NJ;            // 256 columns per block
constexpr int NT = JCHUNK / 16;            // 16 column panels per wave

#if __has_builtin(__builtin_amdgcn_exp2f)
#define EXP2F(x) __builtin_amdgcn_exp2f(x)   // bare v_exp_f32; |arg|<=2.9 safe
#else
#define EXP2F(x) exp2f(x)
#endif

// ZF fragment-major layout: row j, element e  ->  short index
//   (j>>4)*2048 + (e>>3)*128 + (j&15)*8 + (e&7)
// wave fragment load (16-row panel p, k-slice s): contiguous 1KB at
//   p*2048 + s*512 + lane*8   (lane i exactly at byte i*16).

// ------- Kernel A: normalize pair -> ZF rows p & p+B, pos[p] -----------------
__global__ __launch_bounds__(256) void nrm_kernel(const float* __restrict__ ei,
                                                  const float* __restrict__ ej,
                                                  short* __restrict__ zf,
                                                  float* __restrict__ pos,
                                                  float* __restrict__ out) {
    int p    = (blockIdx.x * blockDim.x + threadIdx.x) >> 6;  // pair id
    int lane = threadIdx.x & 63;
    if (p >= B_) return;
    f32x2 a = *(const f32x2*)(ei + (size_t)p * D_ + lane * 2);
    f32x2 b = *(const f32x2*)(ej + (size_t)p * D_ + lane * 2);
    float na = a.x * a.x + a.y * a.y;
    float nb = b.x * b.x + b.y * b.y;
    float dt = a.x * b.x + a.y * b.y;
    #pragma unroll
    for (int m = 1; m < 64; m <<= 1) {
        na += __shfl_xor(na, m);
        nb += __shfl_xor(nb, m);
        dt += __shfl_xor(dt, m);
    }
    float ra = rsqrtf(na), rb = rsqrtf(nb);
    __hip_bfloat162 oa, ob;
    oa.x = __float2bfloat16(a.x * ra); oa.y = __float2bfloat16(a.y * ra);
    ob.x = __float2bfloat16(b.x * rb); ob.y = __float2bfloat16(b.y * rb);
    size_t fi = (size_t)(lane >> 2) * 128 + (p & 15) * 8 + (lane & 3) * 2;
    *(__hip_bfloat162*)(zf + (size_t)(p >> 4) * 2048 + fi)        = oa;
    *(__hip_bfloat162*)(zf + (size_t)((p + B_) >> 4) * 2048 + fi) = ob;
    if (lane == 0) {
        pos[p] = dt * ra * rb;
        if (p == 0) out[0] = 0.0f;
    }
}

// ------- Kernel B: fused sim = ZF ZF^T, exp(2*sim), partial row sums ---------
// 4 waves x 32 rows = 128 rows/block; grid 64 x NJ=32. Small waves (a[2][4])
// keep VGPR <= 128 so 4 waves/SIMD are resident (TLP hides L2 latency).
// All loads contiguous 1KB wave-loads; depth-2 rotating register prefetch;
// bare v_exp_f32; no LDS, no barriers, no atomics.
__global__ __launch_bounds__(256, 4) void simsum_kernel(const short* __restrict__ zf,
                                                        float* __restrict__ part) {
    int lane = threadIdx.x & 63;
    int wave = threadIdx.x >> 6;                        // 0..3
    int r0   = blockIdx.x * BLK_ROWS + wave * 32;       // wave's first row
    int pr0  = r0 >> 4;                                 // 2 A panels
    int pj0  = (blockIdx.y * JCHUNK) >> 4;              // 16 B panels
    int g  = lane >> 4;
    int lm = lane & 15;

    const short* ZA = zf + (size_t)pr0 * 2048 + lane * 8;
    const short* ZB = zf + (size_t)pj0 * 2048 + lane * 8;

    bf16x8 a[2][4];
    #pragma unroll
    for (int t = 0; t < 2; ++t)
        #pragma unroll
        for (int s = 0; s < 4; ++s)
            a[t][s] = *(const bf16x8*)(ZA + t * 2048 + s * 512);

    f32x4 rs[2];
    rs[0] = f32x4{0.f, 0.f, 0.f, 0.f};
    rs[1] = f32x4{0.f, 0.f, 0.f, 0.f};

    bf16x8 b[3][4];
    #pragma unroll
    for (int s = 0; s < 4; ++s) b[0][s] = *(const bf16x8*)(ZB + 0 * 2048 + s * 512);
    #pragma unroll
    for (int s = 0; s < 4; ++s) b[1][s] = *(const bf16x8*)(ZB + 1 * 2048 + s * 512);

    #pragma unroll
    for (int jt = 0; jt < NT; ++jt) {
        if (jt + 2 < NT) {
            #pragma unroll
            for (int s = 0; s < 4; ++s)
                b[(jt + 2) % 3][s] = *(const bf16x8*)(ZB + (size_t)(jt + 2) * 2048 + s * 512);
        }
        f32x4 acc0 = {0.f, 0.f, 0.f, 0.f};
        f32x4 acc1 = {0.f, 0.f, 0.f, 0.f};
        #pragma unroll
        for (int s = 0; s < 4; ++s) {
            acc0 = __builtin_amdgcn_mfma_f32_16x16x32_bf16(a[0][s], b[jt % 3][s], acc0, 0, 0, 0);
            acc1 = __builtin_amdgcn_mfma_f32_16x16x32_bf16(a[1][s], b[jt % 3][s], acc1, 0, 0, 0);
        }
        #pragma unroll
        for (int r = 0; r < 4; ++r) {
            rs[0][r] += EXP2F(EXP2C * acc0[r]);
            rs[1][r] += EXP2F(EXP2C * acc1[r]);
        }
    }

    // reduce partial row sums across the 16 column-lanes (low 4 lane bits)
    #pragma unroll
    for (int m = 1; m < 16; m <<= 1)
        #pragma unroll
        for (int t = 0; t < 2; ++t)
            #pragma unroll
            for (int r = 0; r < 4; ++r)
                rs[t][r] += __shfl_xor(rs[t][r], m);

    // non-atomic partial-sum write: slot (blockIdx.y, row) owned by this wave
    if (lm == 0) {
        float* pr = part + (size_t)blockIdx.y * N_ + r0;
        #pragma unroll
        for (int t = 0; t < 2; ++t)
            #pragma unroll
            for (int r = 0; r < 4; ++r)
                pr[t * 16 + g * 4 + r] = rs[t][r];
    }
}

// ------- Kernel C: loss = mean(log(sum_c part[c][k] - e^2) - 2*pos) ----------
__global__ __launch_bounds__(256) void loss_kernel(const float* __restrict__ part,
                                                   const float* __restrict__ pos,
                                                   float* __restrict__ out) {
    int tid = threadIdx.x;
    int k   = blockIdx.x * 256 + tid;
    float d = 0.0f;
    #pragma unroll
    for (int c = 0; c < NJ; ++c) d += part[(size_t)c * N_ + k];
    d -= E2C;
    float v = __logf(d) - pos[k & (B_ - 1)] * INV_T;
    #pragma unroll
    for (int m = 1; m < 64; m <<= 1) v += __shfl_xor(v, m);
    __shared__ float ps[4];
    if ((tid & 63) == 0) ps[tid >> 6] = v;
    __syncthreads();
    if (tid == 0)
        atomicAdd(out, (ps[0] + ps[1] + ps[2] + ps[3]) * (1.0f / N_));
}

// ------- launch --------------------------------------------------------------
extern "C" void kernel_launch(void* const* d_in, const int* in_sizes, int n_in,
                              void* d_out, int out_size, void* d_ws, size_t ws_size,
                              hipStream_t stream) {
    const float* ei = (const float*)d_in[0];
    const float* ej = (const float*)d_in[1];
    float* out = (float*)d_out;

    short* zf   = (short*)d_ws;                                       // 2 MB
    float* pos  = (float*)((char*)d_ws + (size_t)N_ * D_ * 2);        // 16 KB
    float* part = pos + B_;                                           // NJ*N_*4 = 1 MB

    nrm_kernel<<<dim3(B_ / 4), dim3(256), 0, stream>>>(ei, ej, zf, pos, out);
    simsum_kernel<<<dim3(N_ / BLK_ROWS, NJ), dim3(256), 0, stream>>>(zf, part);
    loss_kernel<<<dim3(N_ / 256), dim3(256), 0, stream>>>(part, pos, out);
}